// Round 12
// baseline (189.322 us; speedup 1.0000x reference)
//
#include <hip/hip_runtime.h>
#include <hip/hip_bf16.h>

#define NN   100000   // nodes
#define EE   500000   // edges
#define MPAD 100096   // 6256 * 16
#define NSTRIP 6256

using bf16x8 = __attribute__((ext_vector_type(8))) short;
using f32x4  = __attribute__((ext_vector_type(4))) float;
using u16x8  = __attribute__((ext_vector_type(8))) unsigned short;

__device__ __forceinline__ unsigned short f2bf(float f) {
  unsigned int x = __builtin_bit_cast(unsigned int, f);
  x += 0x7fffu + ((x >> 16) & 1u);           // round-to-nearest-even
  return (unsigned short)(x >> 16);
}
__device__ __forceinline__ float bf2f(unsigned short u) {
  unsigned int x = ((unsigned int)u) << 16;
  return __builtin_bit_cast(float, x);
}
// HW RNE cvt (compiler emits v_cvt_pk_bf16_f32 for pairs)
__device__ __forceinline__ unsigned short f2bh(float f) {
  return __builtin_bit_cast(unsigned short, __float2bfloat16(f));
}

// ---------------- Pass 1: WT[j][k] = bf16(W1[k + 256*(j>=256)][j&255]) ----------------
__global__ void wprep_kernel(const float* __restrict__ W1, unsigned short* __restrict__ WT) {
  int id = blockIdx.x * blockDim.x + threadIdx.x;
  if (id >= 512 * 32) return;
  int j  = id >> 5;        // 0..511
  int cg = id & 31;        // 8-element k-chunk
  int jc = j & 255;
  int kb = (cg << 3) + ((j >= 256) ? 256 : 0);
  u16x8 v;
#pragma unroll
  for (int t = 0; t < 8; ++t)
    v[t] = f2bf(W1[(size_t)(kb + t) * 256 + jc]);
  *reinterpret_cast<u16x8*>(WT + (size_t)j * 256 + (cg << 3)) = v;
}

// ---------------- Pass 2 (R12): persistent-B, barrier-free, LDS-free GEMM ----------------
// 256 blocks x 512 thr (1 block/CU, 8 waves). Wave w keeps its ENTIRE B-panel
// (cols w*64..+64, K=256) in 128 VGPRs, loaded once. Block strides over 16-row strips;
// per strip each wave: A-frags straight from global via an 8-slot named register ring
// (refilled one full strip ahead -> ~8-consume latency cover), cvt_pk to bf16, 4
// independent MFMAs per K-slice, direct store. NO __syncthreads, NO LDS, NO glds:
// removes the block-synchronous K-step that every 92-118us variant shared.
__global__ __launch_bounds__(512) void gemm_pq(const float* __restrict__ emb,
                                               const unsigned short* __restrict__ WT,
                                               const float* __restrict__ b1,
                                               unsigned short* __restrict__ R) {
  const int t    = threadIdx.x;
  const int lane = t & 63;
  const int wave = t >> 6;                       // colgroup 0..7
  const int fr   = lane & 15, fq = lane >> 4;

  // ---- B panel in registers: B[ks][n]; row = wave*64+16n+fr, k-chunk fq (proven layout)
  bf16x8 B[8][4];
  {
    const unsigned short* wb = WT + (size_t)(wave * 64 + fr) * 256 + (fq << 3);
#pragma unroll
    for (int n = 0; n < 4; ++n)
#pragma unroll
      for (int ks = 0; ks < 8; ++ks)
        B[ks][n] = *(const bf16x8*)(wb + n * 4096 + ks * 32);
  }
  float bn[4];
#pragma unroll
  for (int n = 0; n < 4; ++n) {
    const int c = wave * 64 + 16 * n + fr;
    bn[n] = (c < 256) ? b1[c] : 0.f;
  }

  // ---- A register ring: 8 named slots (lo=first 4 fp32 of the lane's 8, hi=second 4)
  float4 lo0, hi0, lo1, hi1, lo2, hi2, lo3, hi3;
  float4 lo4, hi4, lo5, hi5, lo6, hi6, lo7, hi7;

#define AREF(ptr, k, LO, HI)                                                   \
  do { LO = *(const float4*)((ptr) + (k) * 32);                                \
       HI = *(const float4*)((ptr) + (k) * 32 + 4); } while (0)

#define CONS(ks, LO, HI)                                                       \
  do {                                                                         \
    bf16x8 av;                                                                 \
    av[0] = (short)f2bh(LO.x); av[1] = (short)f2bh(LO.y);                      \
    av[2] = (short)f2bh(LO.z); av[3] = (short)f2bh(LO.w);                      \
    av[4] = (short)f2bh(HI.x); av[5] = (short)f2bh(HI.y);                      \
    av[6] = (short)f2bh(HI.z); av[7] = (short)f2bh(HI.w);                      \
    a0 = __builtin_amdgcn_mfma_f32_16x16x32_bf16(av, B[ks][0], a0, 0, 0, 0);   \
    a1 = __builtin_amdgcn_mfma_f32_16x16x32_bf16(av, B[ks][1], a1, 0, 0, 0);   \
    a2 = __builtin_amdgcn_mfma_f32_16x16x32_bf16(av, B[ks][2], a2, 0, 0, 0);   \
    a3 = __builtin_amdgcn_mfma_f32_16x16x32_bf16(av, B[ks][3], a3, 0, 0, 0);   \
  } while (0)

  int s = blockIdx.x;
  const float* ap;
  {
    int ar = s * 16 + fr; if (ar >= NN) ar = NN - 1;
    ap = emb + (size_t)ar * 256 + (fq << 3);
  }
  // prologue: fill all 8 slots with strip s
  AREF(ap, 0, lo0, hi0); AREF(ap, 1, lo1, hi1);
  AREF(ap, 2, lo2, hi2); AREF(ap, 3, lo3, hi3);
  AREF(ap, 4, lo4, hi4); AREF(ap, 5, lo5, hi5);
  AREF(ap, 6, lo6, hi6); AREF(ap, 7, lo7, hi7);

  while (s < NSTRIP) {
    const int sn = s + 256;
    const bool more = (sn < NSTRIP);
    const float* apn;
    {
      int ar = (more ? sn : s) * 16 + fr; if (ar >= NN) ar = NN - 1;
      apn = emb + (size_t)ar * 256 + (fq << 3);
    }
    f32x4 a0 = {0.f, 0.f, 0.f, 0.f}, a1 = a0, a2 = a0, a3 = a0;

    CONS(0, lo0, hi0); if (more) AREF(apn, 0, lo0, hi0);
    CONS(1, lo1, hi1); if (more) AREF(apn, 1, lo1, hi1);
    CONS(2, lo2, hi2); if (more) AREF(apn, 2, lo2, hi2);
    CONS(3, lo3, hi3); if (more) AREF(apn, 3, lo3, hi3);
    CONS(4, lo4, hi4); if (more) AREF(apn, 4, lo4, hi4);
    CONS(5, lo5, hi5); if (more) AREF(apn, 5, lo5, hi5);
    CONS(6, lo6, hi6); if (more) AREF(apn, 6, lo6, hi6);
    CONS(7, lo7, hi7); if (more) AREF(apn, 7, lo7, hi7);

    // store 16x64 wave tile: col = wave*64 + 16n + fr, row = s*16 + fq*4 + i
    unsigned short* rp = R + (size_t)(s * 16) * 512 + wave * 64;
#pragma unroll
    for (int i = 0; i < 4; ++i) {
      const size_t ro = (size_t)(fq * 4 + i) * 512;
      rp[ro + fr]      = f2bh(a0[i] + bn[0]);
      rp[ro + 16 + fr] = f2bh(a1[i] + bn[1]);
      rp[ro + 32 + fr] = f2bh(a2[i] + bn[2]);
      rp[ro + 48 + fr] = f2bh(a3[i] + bn[3]);
    }
    ap = apn;
    s = sn;
  }
#undef AREF
#undef CONS
}

// ---------------- Pass 3: 8 edges per wave-iteration, 2 edges in flight via lane split ----
// score[e] = b2 + sum_j relu(R[src][j] + R[dst][256+j]) * W2[j]   (b1 pre-folded into R)
__global__ __launch_bounds__(256) void edge_kernel(const int* __restrict__ idx,
                                                   const unsigned short* __restrict__ R,
                                                   const float* __restrict__ W2,
                                                   const float* __restrict__ b2,
                                                   float* __restrict__ out) {
  const int lane  = threadIdx.x & 63;
  const int half  = lane >> 5;         // which of the 2 concurrent edges this lane serves
  const int l     = lane & 31;         // 32 lanes x 8 channels = 256 channels
  const int gwave = (int)((blockIdx.x * blockDim.x + threadIdx.x) >> 6);
  const int nwave = (int)((gridDim.x * blockDim.x) >> 6);
  const float4 w0 = *(const float4*)(W2 + (l << 3));
  const float4 w1 = *(const float4*)(W2 + (l << 3) + 4);
  const float bias = b2[0];

  for (int c = gwave; c < (EE / 8); c += nwave) {
    const int e0 = c << 3;
    int s[4], d[4];
#pragma unroll
    for (int u = 0; u < 4; ++u) {                // edge for this lane: e0 + 2u + half
      s[u] = idx[e0 + (u << 1) + half];
      d[u] = idx[EE + e0 + (u << 1) + half];
    }
    u16x8 ga[4], gb[4];
#pragma unroll
    for (int u = 0; u < 4; ++u) {                // issue all 16 gathers before reducing
      ga[u] = *(const u16x8*)(R + (size_t)s[u] * 512 + (l << 3));
      gb[u] = *(const u16x8*)(R + (size_t)d[u] * 512 + 256 + (l << 3));
    }
#pragma unroll
    for (int u = 0; u < 4; ++u) {
      float acc;
      acc  = fmaxf(bf2f((unsigned short)ga[u][0]) + bf2f((unsigned short)gb[u][0]), 0.f) * w0.x;
      acc += fmaxf(bf2f((unsigned short)ga[u][1]) + bf2f((unsigned short)gb[u][1]), 0.f) * w0.y;
      acc += fmaxf(bf2f((unsigned short)ga[u][2]) + bf2f((unsigned short)gb[u][2]), 0.f) * w0.z;
      acc += fmaxf(bf2f((unsigned short)ga[u][3]) + bf2f((unsigned short)gb[u][3]), 0.f) * w0.w;
      acc += fmaxf(bf2f((unsigned short)ga[u][4]) + bf2f((unsigned short)gb[u][4]), 0.f) * w1.x;
      acc += fmaxf(bf2f((unsigned short)ga[u][5]) + bf2f((unsigned short)gb[u][5]), 0.f) * w1.y;
      acc += fmaxf(bf2f((unsigned short)ga[u][6]) + bf2f((unsigned short)gb[u][6]), 0.f) * w1.z;
      acc += fmaxf(bf2f((unsigned short)ga[u][7]) + bf2f((unsigned short)gb[u][7]), 0.f) * w1.w;
#pragma unroll
      for (int off = 16; off > 0; off >>= 1) acc += __shfl_xor(acc, off, 64);
      if (l == 0) out[e0 + (u << 1) + half] = acc + bias;
    }
  }
}

// ---------------- Fallback (only if ws is too small): direct, slow, correct ----------------
__global__ __launch_bounds__(256) void fallback_kernel(const float* __restrict__ emb,
                                                       const int* __restrict__ idx,
                                                       const float* __restrict__ W1,
                                                       const float* __restrict__ b1,
                                                       const float* __restrict__ W2,
                                                       const float* __restrict__ b2,
                                                       float* __restrict__ out) {
  __shared__ float feats[512];
  __shared__ float red[256];
  const int t = threadIdx.x;
  for (int e = blockIdx.x; e < EE; e += gridDim.x) {
    __syncthreads();
    const int s = idx[e], d = idx[EE + e];
    feats[t]       = emb[(size_t)s * 256 + t];
    feats[256 + t] = emb[(size_t)d * 256 + t];
    __syncthreads();
    float h = b1[t];
    for (int k = 0; k < 512; ++k) h += feats[k] * W1[k * 256 + t];
    red[t] = fmaxf(h, 0.f) * W2[t];
    __syncthreads();
    for (int off = 128; off > 0; off >>= 1) {
      if (t < off) red[t] += red[t + off];
      __syncthreads();
    }
    if (t == 0) out[e] = red[0] + b2[0];
  }
}

extern "C" void kernel_launch(void* const* d_in, const int* in_sizes, int n_in,
                              void* d_out, int out_size, void* d_ws, size_t ws_size,
                              hipStream_t stream) {
  const float* emb = (const float*)d_in[0];
  const int*   idx = (const int*)d_in[1];
  const float* W1  = (const float*)d_in[2];
  const float* b1  = (const float*)d_in[3];
  const float* W2  = (const float*)d_in[4];
  const float* b2  = (const float*)d_in[5];
  float* out = (float*)d_out;

  const size_t wt_elems = (size_t)512 * 256;
  const size_t r_elems  = (size_t)MPAD * 512;
  const size_t need = (wt_elems + r_elems) * sizeof(unsigned short);

  if (ws_size < need) {
    fallback_kernel<<<4096, 256, 0, stream>>>(emb, idx, W1, b1, W2, b2, out);
    return;
  }

  unsigned short* WT = (unsigned short*)d_ws;
  unsigned short* R  = WT + wt_elems;

  wprep_kernel<<<64, 256, 0, stream>>>(W1, WT);
  gemm_pq<<<256, 512, 0, stream>>>(emb, WT, b1, R);
  edge_kernel<<<2048, 256, 0, stream>>>(idx, R, W2, b2, out);
}

// Round 13
// 138.782 us; speedup vs baseline: 1.3642x; 1.3642x over previous
//
#include <hip/hip_runtime.h>
#include <hip/hip_bf16.h>

#define NN   100000   // nodes
#define EE   500000   // edges
#define MPAD 100096   // 782 * 128

using bf16x8 = __attribute__((ext_vector_type(8))) short;
using f32x4  = __attribute__((ext_vector_type(4))) float;
using u16x8  = __attribute__((ext_vector_type(8))) unsigned short;

__device__ __forceinline__ unsigned short f2bf(float f) {
  unsigned int x = __builtin_bit_cast(unsigned int, f);
  x += 0x7fffu + ((x >> 16) & 1u);           // round-to-nearest-even
  return (unsigned short)(x >> 16);
}
__device__ __forceinline__ float bf2f(unsigned short u) {
  unsigned int x = ((unsigned int)u) << 16;
  return __builtin_bit_cast(float, x);
}
// HW RNE cvt (compiler emits v_cvt_pk_bf16_f32 for pairs)
__device__ __forceinline__ unsigned short f2bh(float f) {
  return __builtin_bit_cast(unsigned short, __float2bfloat16(f));
}
__device__ __forceinline__ void glds16(const void* g, const void* l) {
  __builtin_amdgcn_global_load_lds((const __attribute__((address_space(1))) void*)g,
                                   (__attribute__((address_space(3))) void*)l, 16, 0, 0);
}

// ---------------- Pass 1: WT[j][k] = bf16(W1[k + 256*(j>=256)][j&255]) ----------------
__global__ void wprep_kernel(const float* __restrict__ W1, unsigned short* __restrict__ WT) {
  int id = blockIdx.x * blockDim.x + threadIdx.x;
  if (id >= 512 * 32) return;
  int j  = id >> 5;        // 0..511
  int cg = id & 31;        // 8-element k-chunk
  int jc = j & 255;
  int kb = (cg << 3) + ((j >= 256) ? 256 : 0);
  u16x8 v;
#pragma unroll
  for (int t = 0; t < 8; ++t)
    v[t] = f2bf(W1[(size_t)(kb + t) * 256 + jc]);
  *reinterpret_cast<u16x8*>(WT + (size_t)j * 256 + (cg << 3)) = v;
}

// ---------------- Pass 2: R[MPAD][512] bf16 = emb @ WT^T (+ b1 on src half) ----------------
// EXACT R5 kernel (best measured: 92us, 0 bank conflicts, VGPR 68) with ONE change:
// __launch_bounds__(256, 4). 4 blocks/CU = 128KB LDS (fits; 5x32=160KB did NOT, R11) and
// VGPR cap 128 >> 68 (no spill pressure, unlike (256,5) which squeezed to 48 and spilled).
// Occupancy cap 12 -> 16 waves/CU. Single-variable TLP test.
__global__ __launch_bounds__(256, 4) void gemm_pq(const float* __restrict__ emb,
                                                  const unsigned short* __restrict__ WT,
                                                  const float* __restrict__ b1,
                                                  unsigned short* __restrict__ R) {
  __shared__ unsigned short ldsA[2][128 * 32];
  __shared__ unsigned short ldsB[2][128 * 32];

  const int t    = threadIdx.x;
  const int lane = t & 63;
  const int wave = t >> 6;
  const int wrow = wave >> 1, wcol = wave & 1;
  // XCD-bijective swizzle: 3128 = 8 * 391; n-tiles (lid&3) of one m-tile share an XCD L2.
  const int bid = (int)blockIdx.x;
  const int lid = (bid & 7) * 391 + (bid >> 3);
  const int m0 = (lid >> 2) * 128;
  const int n0 = (lid & 3) * 128;

  // ---- A staging: thread -> row a_r = t>>1, half a_h = t&1 (16 fp32 -> chunks 2h,2h+1)
  const int a_r = t >> 1, a_h = t & 1;
  int arow_g = m0 + a_r; if (arow_g >= NN) arow_g = NN - 1;   // clamp (pad rows unused)
  const float* aSrc = emb + (size_t)arow_g * 256 + (a_h << 4);
  const int a_s  = (a_r >> 1) & 3;
  const int aW0  = a_r * 32 + ((((a_h << 1) | 0) ^ a_s) << 3);
  const int aW1  = a_r * 32 + ((((a_h << 1) | 1) ^ a_s) << 3);

  // ---- B staging (glds): per wave 2 instrs of 1 KB; lane -> row l>>2, q'=l&3
  size_t bOff[2]; int bLds[2];
#pragma unroll
  for (int i = 0; i < 2; ++i) {
    const int r  = wave * 32 + i * 16 + (lane >> 2);
    const int qp = lane & 3;
    const int g  = qp ^ ((r >> 1) & 3);              // pre-swizzled global chunk
    bOff[i] = (size_t)(n0 + r) * 256 + (g << 3);
    bLds[i] = (wave * 32 + i * 16) * 32;             // wave-uniform base (elems)
  }

  // ---- fragment read offsets (R1-proven formula, 0 conflicts)
  const int fr = lane & 15, fq = lane >> 4;
  int aoff[4], boff[4];
#pragma unroll
  for (int m = 0; m < 4; ++m) {
    const int r = wrow * 64 + 16 * m + fr;
    aoff[m] = r * 32 + ((fq ^ ((r >> 1) & 3)) << 3);
  }
#pragma unroll
  for (int n = 0; n < 4; ++n) {
    const int r = wcol * 64 + 16 * n + fr;
    boff[n] = r * 32 + ((fq ^ ((r >> 1) & 3)) << 3);
  }

  f32x4 acc[4][4] = {};
  float4 pA[4];

#define ALOAD(kb)                                                              \
  do {                                                                         \
    pA[0] = *(const float4*)(aSrc + (kb));                                     \
    pA[1] = *(const float4*)(aSrc + (kb) + 4);                                 \
    pA[2] = *(const float4*)(aSrc + (kb) + 8);                                 \
    pA[3] = *(const float4*)(aSrc + (kb) + 12);                                \
  } while (0)

#define AWRITE(buf)                                                            \
  do {                                                                         \
    u16x8 w0, w1;                                                              \
    w0[0] = f2bh(pA[0].x); w0[1] = f2bh(pA[0].y);                              \
    w0[2] = f2bh(pA[0].z); w0[3] = f2bh(pA[0].w);                              \
    w0[4] = f2bh(pA[1].x); w0[5] = f2bh(pA[1].y);                              \
    w0[6] = f2bh(pA[1].z); w0[7] = f2bh(pA[1].w);                              \
    w1[0] = f2bh(pA[2].x); w1[1] = f2bh(pA[2].y);                              \
    w1[2] = f2bh(pA[2].z); w1[3] = f2bh(pA[2].w);                              \
    w1[4] = f2bh(pA[3].x); w1[5] = f2bh(pA[3].y);                              \
    w1[6] = f2bh(pA[3].z); w1[7] = f2bh(pA[3].w);                              \
    *(u16x8*)&ldsA[(buf)][aW0] = w0;                                           \
    *(u16x8*)&ldsA[(buf)][aW1] = w1;                                           \
  } while (0)

#define BGLDS(buf, kb)                                                         \
  do {                                                                         \
    glds16(WT + bOff[0] + (kb), &ldsB[(buf)][bLds[0]]);                        \
    glds16(WT + bOff[1] + (kb), &ldsB[(buf)][bLds[1]]);                        \
  } while (0)

  // prologue
  ALOAD(0);
  AWRITE(0);
  BGLDS(0, 0);
  ALOAD(32);
  __syncthreads();

#pragma unroll
  for (int ks = 0; ks < 8; ++ks) {
    const int p = ks & 1;
    if (ks < 7) {
      BGLDS(p ^ 1, (ks + 1) * 32);     // DMA next B (in flight across compute)
      AWRITE(p ^ 1);                   // pA aged 1 iter -> counted vmcnt, no stall
      if (ks < 6) ALOAD((ks + 2) * 32);
    }
    bf16x8 av[4], bv[4];
#pragma unroll
    for (int m = 0; m < 4; ++m) av[m] = *(const bf16x8*)&ldsA[p][aoff[m]];
#pragma unroll
    for (int n = 0; n < 4; ++n) bv[n] = *(const bf16x8*)&ldsB[p][boff[n]];
#pragma unroll
    for (int m = 0; m < 4; ++m)
#pragma unroll
      for (int n = 0; n < 4; ++n)
        acc[m][n] = __builtin_amdgcn_mfma_f32_16x16x32_bf16(av[m], bv[n], acc[m][n], 0, 0, 0);
    if (ks < 7) __syncthreads();
  }

  // epilogue: col = lane&15 (+16n), row = (lane>>4)*4 + i; m-outer/n-inner (clean 128B lines)
  float bn[4];
#pragma unroll
  for (int n = 0; n < 4; ++n) {
    const int c = n0 + wcol * 64 + 16 * n + fr;
    bn[n] = (c < 256) ? b1[c] : 0.f;
  }
#pragma unroll
  for (int m = 0; m < 4; ++m) {
    const int r0 = m0 + wrow * 64 + 16 * m + (fq << 2);
#pragma unroll
    for (int n = 0; n < 4; ++n) {
      const int c = n0 + wcol * 64 + 16 * n + fr;
#pragma unroll
      for (int i = 0; i < 4; ++i)
        R[(size_t)(r0 + i) * 512 + c] = f2bh(acc[m][n][i] + bn[n]);
    }
  }
#undef ALOAD
#undef AWRITE
#undef BGLDS
}

// ---------------- Pass 3: 8 edges per wave-iteration, 2 edges in flight via lane split ----
// score[e] = b2 + sum_j relu(R[src][j] + R[dst][256+j]) * W2[j]   (b1 pre-folded into R)
__global__ __launch_bounds__(256) void edge_kernel(const int* __restrict__ idx,
                                                   const unsigned short* __restrict__ R,
                                                   const float* __restrict__ W2,
                                                   const float* __restrict__ b2,
                                                   float* __restrict__ out) {
  const int lane  = threadIdx.x & 63;
  const int half  = lane >> 5;         // which of the 2 concurrent edges this lane serves
  const int l     = lane & 31;         // 32 lanes x 8 channels = 256 channels
  const int gwave = (int)((blockIdx.x * blockDim.x + threadIdx.x) >> 6);
  const int nwave = (int)((gridDim.x * blockDim.x) >> 6);
  const float4 w0 = *(const float4*)(W2 + (l << 3));
  const float4 w1 = *(const float4*)(W2 + (l << 3) + 4);
  const float bias = b2[0];

  for (int c = gwave; c < (EE / 8); c += nwave) {
    const int e0 = c << 3;
    int s[4], d[4];
#pragma unroll
    for (int u = 0; u < 4; ++u) {                // edge for this lane: e0 + 2u + half
      s[u] = idx[e0 + (u << 1) + half];
      d[u] = idx[EE + e0 + (u << 1) + half];
    }
    u16x8 ga[4], gb[4];
#pragma unroll
    for (int u = 0; u < 4; ++u) {                // issue all 16 gathers before reducing
      ga[u] = *(const u16x8*)(R + (size_t)s[u] * 512 + (l << 3));
      gb[u] = *(const u16x8*)(R + (size_t)d[u] * 512 + 256 + (l << 3));
    }
#pragma unroll
    for (int u = 0; u < 4; ++u) {
      float acc;
      acc  = fmaxf(bf2f((unsigned short)ga[u][0]) + bf2f((unsigned short)gb[u][0]), 0.f) * w0.x;
      acc += fmaxf(bf2f((unsigned short)ga[u][1]) + bf2f((unsigned short)gb[u][1]), 0.f) * w0.y;
      acc += fmaxf(bf2f((unsigned short)ga[u][2]) + bf2f((unsigned short)gb[u][2]), 0.f) * w0.z;
      acc += fmaxf(bf2f((unsigned short)ga[u][3]) + bf2f((unsigned short)gb[u][3]), 0.f) * w0.w;
      acc += fmaxf(bf2f((unsigned short)ga[u][4]) + bf2f((unsigned short)gb[u][4]), 0.f) * w1.x;
      acc += fmaxf(bf2f((unsigned short)ga[u][5]) + bf2f((unsigned short)gb[u][5]), 0.f) * w1.y;
      acc += fmaxf(bf2f((unsigned short)ga[u][6]) + bf2f((unsigned short)gb[u][6]), 0.f) * w1.z;
      acc += fmaxf(bf2f((unsigned short)ga[u][7]) + bf2f((unsigned short)gb[u][7]), 0.f) * w1.w;
#pragma unroll
      for (int off = 16; off > 0; off >>= 1) acc += __shfl_xor(acc, off, 64);
      if (l == 0) out[e0 + (u << 1) + half] = acc + bias;
    }
  }
}

// ---------------- Fallback (only if ws is too small): direct, slow, correct ----------------
__global__ __launch_bounds__(256) void fallback_kernel(const float* __restrict__ emb,
                                                       const int* __restrict__ idx,
                                                       const float* __restrict__ W1,
                                                       const float* __restrict__ b1,
                                                       const float* __restrict__ W2,
                                                       const float* __restrict__ b2,
                                                       float* __restrict__ out) {
  __shared__ float feats[512];
  __shared__ float red[256];
  const int t = threadIdx.x;
  for (int e = blockIdx.x; e < EE; e += gridDim.x) {
    __syncthreads();
    const int s = idx[e], d = idx[EE + e];
    feats[t]       = emb[(size_t)s * 256 + t];
    feats[256 + t] = emb[(size_t)d * 256 + t];
    __syncthreads();
    float h = b1[t];
    for (int k = 0; k < 512; ++k) h += feats[k] * W1[k * 256 + t];
    red[t] = fmaxf(h, 0.f) * W2[t];
    __syncthreads();
    for (int off = 128; off > 0; off >>= 1) {
      if (t < off) red[t] += red[t + off];
      __syncthreads();
    }
    if (t == 0) out[e] = red[0] + b2[0];
  }
}

extern "C" void kernel_launch(void* const* d_in, const int* in_sizes, int n_in,
                              void* d_out, int out_size, void* d_ws, size_t ws_size,
                              hipStream_t stream) {
  const float* emb = (const float*)d_in[0];
  const int*   idx = (const int*)d_in[1];
  const float* W1  = (const float*)d_in[2];
  const float* b1  = (const float*)d_in[3];
  const float* W2  = (const float*)d_in[4];
  const float* b2  = (const float*)d_in[5];
  float* out = (float*)d_out;

  const size_t wt_elems = (size_t)512 * 256;
  const size_t r_elems  = (size_t)MPAD * 512;
  const size_t need = (wt_elems + r_elems) * sizeof(unsigned short);

  if (ws_size < need) {
    fallback_kernel<<<4096, 256, 0, stream>>>(emb, idx, W1, b1, W2, b2, out);
    return;
  }

  unsigned short* WT = (unsigned short*)d_ws;
  unsigned short* R  = WT + wt_elems;

  wprep_kernel<<<64, 256, 0, stream>>>(W1, WT);
  gemm_pq<<<(MPAD / 128) * 4, 256, 0, stream>>>(emb, WT, b1, R);
  edge_kernel<<<2048, 256, 0, stream>>>(idx, R, W2, b2, out);
}